// Round 6
// baseline (150.847 us; speedup 1.0000x reference)
//
#include <hip/hip_runtime.h>

#define BATCH 8192
#define LOSC  2048.0f
#define LOINV (1.0f / 2048.0f)

typedef _Float16 f16x8 __attribute__((ext_vector_type(8)));
typedef __fp16   fp16x2 __attribute__((ext_vector_type(2)));
typedef float    f32x4 __attribute__((ext_vector_type(4)));

union PK2 { fp16x2 h; unsigned u; };
union U8  { f16x8 v; unsigned u[4]; };

// fwd-lane bit pattern: lanes with (lane&8)==0 (bits 0-7,16-23,32-39,48-55)
#define FWDMASK 0x00FF00FF00FF00FFULL

// pack two f32 -> 2 f16 via v_cvt_pkrtz (RTZ is fine for hi/lo splitting:
// any hi with |v-hi| <= ulp works; lo carries the remainder, scaled 2^11)
__device__ __forceinline__ unsigned pkrtz(float a, float b) {
    PK2 p; p.h = __builtin_amdgcn_cvt_pkrtz(a, b); return p.u;
}

// Packed lo residual in 2 instrs/pair: f16x2{ (a-hi0)*2048, (b-hi1)*2048 }
// computed as fma(hi, -2048, v*2048) per half via v_fma_mixlo/hi_f16.
// Intermediate is f32-exact (v-hi Sterbenz-exact, *2048 exact).
__device__ __forceinline__ unsigned lopair(unsigned hipk, float am, float bm,
                                           float n2048) {
    unsigned d;
    asm("v_fma_mixlo_f16 %0, %1, %2, %3 op_sel:[0,0,0] op_sel_hi:[1,0,0]\n\t"
        "v_fma_mixhi_f16 %0, %1, %2, %4 op_sel:[1,0,0] op_sel_hi:[1,0,0]"
        : "=&v"(d)
        : "v"(hipk), "v"(n2048), "v"(am), "v"(bm));
    return d;
}

// lane i <-> lane i^8 exchange via DPP ROW_ROR:8 (rotate by 8 within each
// 16-lane row == xor-8, self-inverse). Single VALU mov, no DS pipe.
__device__ __forceinline__ float xor8f(float v) {
    const int r = __builtin_amdgcn_mov_dpp(__builtin_bit_cast(int, v),
                                           0x128 /*ROW_ROR:8*/, 0xf, 0xf, false);
    return __builtin_bit_cast(float, r);
}

// gated select by a wave-uniform 64-bit lane mask held in SGPRs:
// r = (m >> lane) & 1 ? v : 0, as a single v_cndmask with s-pair source.
__device__ __forceinline__ float selmask(float v, unsigned long long m) {
    float r;
    asm("v_cndmask_b32 %0, 0, %1, %2" : "=v"(r) : "v"(v), "s"(m));
    return r;
}

// butterfly-sum with lane^16 / lane^32 partner via v_permlane16/32_swap.
// R4 BUG + FIX: with `float a=g, b=g;` the RA coalesced a and b into ONE
// vreg (b is an IR copy of a), emitting `v_permlane16_swap v0, v0` — a
// degenerate self-swap that computed 2*g[partner] instead of own+partner
// (observed absmax 0.14 = gradient-scale corruption). The opaque v_mov
// below defines b via asm so it CANNOT be coalesced with a; both are live
// into the swap -> provably distinct physregs. After the swap the two regs
// jointly hold {own, partner} per lane (either row-swap convention), so
// a+b == g + g^N bitwise (fp add commutative). Pure VALU, no DS pipe.
__device__ __forceinline__ float bfly16(float g) {
    float a = g, b;
    asm volatile("v_mov_b32 %0, %1" : "=v"(b) : "v"(g));
    asm("v_permlane16_swap_b32 %0, %1" : "+v"(a), "+v"(b));
    return a + b;
}
__device__ __forceinline__ float bfly32(float g) {
    float a = g, b;
    asm volatile("v_mov_b32 %0, %1" : "=v"(b) : "v"(g));
    asm("v_permlane32_swap_b32 %0, %1" : "+v"(a), "+v"(b));
    return a + b;
}

// ---------------------------------------------------------------------------
// Fused kernel: NN prologue (exact |dx| scan, first-index argmin, self
// excluded) + 50-step GD solve. 8 samples/wave, 1024 blocks x 1 wave
// (1 wave/SIMD; grid-capped). Loop is VALU-issue/latency bound.
// R4 design (retained): (1) partner-sign broadcast via __ballot + SALU
// shift-or + s-pair cndmask, (2) L4 computed tangent-locally (one g-DPP
// instead of 16 value-DPPs), (3) final q-quadrant reduction via
// permlane16/32_swap butterflies (no DS ops in the GD loop).
// R6 change: bfly aliasing fix only (see bfly16 comment).
// K=32 MFMA layout as before (zero-shfl inter-layer transform).
// B cols = [8 fwd | 8 tangent].
// ---------------------------------------------------------------------------
__global__ __launch_bounds__(64, 1) void solve_kernel(
    const float* __restrict__ x, const float* __restrict__ c,
    const float* __restrict__ W1, const float* __restrict__ b1,
    const float* __restrict__ W2, const float* __restrict__ b2,
    const float* __restrict__ W3, const float* __restrict__ b3,
    const float* __restrict__ W4, float* __restrict__ out)
{
    const int lane  = threadIdx.x & 63;
    const int sbase = blockIdx.x * 8;
    const float n2048 = -2048.0f;

    // ---- stage all c into LDS (32 KiB) ----
    __shared__ float cs[BATCH];
    {
        const float4* cg = (const float4*)c;
        float4* cl = (float4*)cs;
        #pragma unroll
        for (int j = 0; j < BATCH / 4 / 64; ++j)
            cl[lane + j * 64] = cg[lane + j * 64];
    }
    __syncthreads();

    // ---- fused NN: 8 lanes per sample scan 2048 float4 each ----
    // Two-phase body: issue 16 ds_read_b128 into a register buffer, then
    // process — 16 reads in flight amortize LDS latency.
    float c0s;
    {
        const int g  = lane >> 3;
        const int p  = lane & 7;
        const int si = sbase + g;
        const float ci = cs[si];
        const int sj0 = ((si & 3) == 0) ? (si >> 2) : -1;
        const int sj1 = ((si & 3) == 1) ? (si >> 2) : -1;
        const int sj2 = ((si & 3) == 2) ? (si >> 2) : -1;
        const int sj3 = ((si & 3) == 3) ? (si >> 2) : -1;
        const float4* cs4 = (const float4*)cs;
        float bd0 = 3e38f, bd1 = 3e38f, bd2 = 3e38f, bd3 = 3e38f;
        int   bj0 = 0,     bj1 = 0,     bj2 = 0,     bj3 = 0;
        #pragma unroll 1
        for (int big = 0; big < 16; ++big) {
            float4 vv[16];
            #pragma unroll
            for (int u = 0; u < 16; ++u)
                vv[u] = cs4[p + (big * 16 + u) * 8];
            #pragma unroll
            for (int u = 0; u < 16; ++u) {
                const int jj = p + (big * 16 + u) * 8;
                const float4 v = vv[u];
                float d0 = fabsf(ci - v.x);
                float d1 = fabsf(ci - v.y);
                float d2 = fabsf(ci - v.z);
                float d3 = fabsf(ci - v.w);
                if (jj == sj0) d0 = 3e38f;
                if (jj == sj1) d1 = 3e38f;
                if (jj == sj2) d2 = 3e38f;
                if (jj == sj3) d3 = 3e38f;
                if (d0 < bd0) { bd0 = d0; bj0 = jj; }
                if (d1 < bd1) { bd1 = d1; bj1 = jj; }
                if (d2 < bd2) { bd2 = d2; bj2 = jj; }
                if (d3 < bd3) { bd3 = d3; bj3 = jj; }
            }
        }
        float best = bd0; int bestj = bj0 * 4 + 0;
        { const int j1 = bj1 * 4 + 1; if (bd1 < best || (bd1 == best && j1 < bestj)) { best = bd1; bestj = j1; } }
        { const int j2 = bj2 * 4 + 2; if (bd2 < best || (bd2 == best && j2 < bestj)) { best = bd2; bestj = j2; } }
        { const int j3 = bj3 * 4 + 3; if (bd3 < best || (bd3 == best && j3 < bestj)) { best = bd3; bestj = j3; } }
        #pragma unroll
        for (int off = 1; off < 8; off <<= 1) {
            const float od = __shfl_xor(best, off);
            const int   oj = __shfl_xor(bestj, off);
            if (od < best || (od == best && oj < bestj)) { best = od; bestj = oj; }
        }
        const float bestc = cs[bestj];
        c0s = __shfl(bestc, (lane & 7) << 3);
    }

    // ---- GD solve ----
    const int q  = lane >> 4;
    const int cc = lane & 15;
    const bool fwd = (cc < 8);
    const int s = cc & 7;

    // ---- W2/W3 hi+lo fragments (K=32 chunks), all in registers ----
    f16x8 W2h[4][2], W2l[4][2], W3h[4][2], W3l[4][2];
    #pragma unroll
    for (int T = 0; T < 4; ++T)
        #pragma unroll
        for (int M = 0; M < 2; ++M) {
            const int off0 = (T * 16 + cc) * 64 + M * 32 + q * 4;
            const int off1 = off0 + 16;
            float4 a = *(const float4*)(W2 + off0);
            float4 b = *(const float4*)(W2 + off1);
            U8 h, l;
            h.u[0] = pkrtz(a.x, a.y); h.u[1] = pkrtz(a.z, a.w);
            h.u[2] = pkrtz(b.x, b.y); h.u[3] = pkrtz(b.z, b.w);
            l.u[0] = lopair(h.u[0], a.x * LOSC, a.y * LOSC, n2048);
            l.u[1] = lopair(h.u[1], a.z * LOSC, a.w * LOSC, n2048);
            l.u[2] = lopair(h.u[2], b.x * LOSC, b.y * LOSC, n2048);
            l.u[3] = lopair(h.u[3], b.z * LOSC, b.w * LOSC, n2048);
            W2h[T][M] = h.v; W2l[T][M] = l.v;
            a = *(const float4*)(W3 + off0);
            b = *(const float4*)(W3 + off1);
            h.u[0] = pkrtz(a.x, a.y); h.u[1] = pkrtz(a.z, a.w);
            h.u[2] = pkrtz(b.x, b.y); h.u[3] = pkrtz(b.z, b.w);
            l.u[0] = lopair(h.u[0], a.x * LOSC, a.y * LOSC, n2048);
            l.u[1] = lopair(h.u[1], a.z * LOSC, a.w * LOSC, n2048);
            l.u[2] = lopair(h.u[2], b.x * LOSC, b.y * LOSC, n2048);
            l.u[3] = lopair(h.u[3], b.z * LOSC, b.w * LOSC, n2048);
            W3h[T][M] = h.v; W3l[T][M] = l.v;
        }

    // ---- biases as f32x4 (direct MFMA C-operands) + W4 rows ----
    f32x4 b2q[4], b3q[4];
    const f32x4 zq = {0.f, 0.f, 0.f, 0.f};
    float w4r[16];
    #pragma unroll
    for (int T = 0; T < 4; ++T)
        #pragma unroll
        for (int r = 0; r < 4; ++r) {
            const int row = T * 16 + q * 4 + r;
            b2q[T][r] = fwd ? b2[row] : 0.f;
            b3q[T][r] = fwd ? b3[row] : 0.f;
            w4r[T * 4 + r] = W4[row];
        }

    // ---- layer-1 constants: logical k = m*16 + q*4 + j ----
    float A1v[16], w11v[16];
    {
        const float xs = x[sbase + s];
        #pragma unroll
        for (int m = 0; m < 4; ++m)
            #pragma unroll
            for (int j = 0; j < 4; ++j) {
                const int k = m * 16 + q * 4 + j;
                w11v[m * 4 + j] = W1[k * 3 + 1];
                A1v[m * 4 + j]  = fmaf(xs, W1[k * 3 + 0],
                                       fmaf(c0s, W1[k * 3 + 2], b1[k]));
            }
    }

    float y = 0.0f;

    #pragma unroll 1
    for (int step = 0; step < 50; ++step) {
        // ---- layer 1 (fp32, registers) -> split B1 chunks (2 x K=32) ----
        U8 B1h[2], B1l[2];
        #pragma unroll
        for (int m = 0; m < 4; ++m) {
            float v[4];
            #pragma unroll
            for (int j = 0; j < 4; ++j) {
                const float w = w11v[m * 4 + j];
                const float z = fmaf(y, w, A1v[m * 4 + j]);
                const float a = fwd ? z : w;
                v[j] = (z > 0.f) ? a : 0.f;
            }
            const unsigned h0 = pkrtz(v[0], v[1]);
            const unsigned h1 = pkrtz(v[2], v[3]);
            const int M = m >> 1, o = (m & 1) * 2;
            B1h[M].u[o]     = h0;
            B1h[M].u[o + 1] = h1;
            B1l[M].u[o]     = lopair(h0, v[0] * LOSC, v[1] * LOSC, n2048);
            B1l[M].u[o + 1] = lopair(h1, v[2] * LOSC, v[3] * LOSC, n2048);
        }
        // ---- layer 2: split MFMA (bias rides in as C-operand) ----
        f32x4 ZH[4], ZL[4];
        #pragma unroll
        for (int T = 0; T < 4; ++T) {
            f32x4 aH = __builtin_amdgcn_mfma_f32_16x16x32_f16(W2h[T][0], B1h[0].v, b2q[T], 0, 0, 0);
            f32x4 aL = __builtin_amdgcn_mfma_f32_16x16x32_f16(W2h[T][0], B1l[0].v, zq, 0, 0, 0);
            aL = __builtin_amdgcn_mfma_f32_16x16x32_f16(W2l[T][0], B1h[0].v, aL, 0, 0, 0);
            aH = __builtin_amdgcn_mfma_f32_16x16x32_f16(W2h[T][1], B1h[1].v, aH, 0, 0, 0);
            aL = __builtin_amdgcn_mfma_f32_16x16x32_f16(W2h[T][1], B1l[1].v, aL, 0, 0, 0);
            aL = __builtin_amdgcn_mfma_f32_16x16x32_f16(W2l[T][1], B1h[1].v, aL, 0, 0, 0);
            ZH[T] = aH; ZL[T] = aL;
        }
        // ---- combine + mask -> B2 chunks. Gate = fwd lane's primal sign,
        // broadcast to tangent partner via ballot + SALU shift-or (no DPP,
        // no value exchange: each lane selects its OWN z). ----
        {
            float zv[16];
            #pragma unroll
            for (int i = 0; i < 16; ++i)
                zv[i] = fmaf(ZL[i >> 2][i & 3], LOINV, ZH[i >> 2][i & 3]);
            U8 B2h[2], B2l[2];
            #pragma unroll
            for (int T = 0; T < 4; ++T) {
                float v[4];
                #pragma unroll
                for (int r = 0; r < 4; ++r) {
                    const unsigned long long mb = __ballot(zv[T * 4 + r] > 0.f);
                    const unsigned long long t  = mb & FWDMASK;
                    v[r] = selmask(zv[T * 4 + r], t | (t << 8));
                }
                const unsigned h0 = pkrtz(v[0], v[1]);
                const unsigned h1 = pkrtz(v[2], v[3]);
                const int M = T >> 1, o = (T & 1) * 2;
                B2h[M].u[o]     = h0;
                B2h[M].u[o + 1] = h1;
                B2l[M].u[o]     = lopair(h0, v[0] * LOSC, v[1] * LOSC, n2048);
                B2l[M].u[o + 1] = lopair(h1, v[2] * LOSC, v[3] * LOSC, n2048);
            }
            // ---- layer 3: split MFMA ----
            #pragma unroll
            for (int T = 0; T < 4; ++T) {
                f32x4 aH = __builtin_amdgcn_mfma_f32_16x16x32_f16(W3h[T][0], B2h[0].v, b3q[T], 0, 0, 0);
                f32x4 aL = __builtin_amdgcn_mfma_f32_16x16x32_f16(W3h[T][0], B2l[0].v, zq, 0, 0, 0);
                aL = __builtin_amdgcn_mfma_f32_16x16x32_f16(W3l[T][0], B2h[0].v, aL, 0, 0, 0);
                aH = __builtin_amdgcn_mfma_f32_16x16x32_f16(W3h[T][1], B2h[1].v, aH, 0, 0, 0);
                aL = __builtin_amdgcn_mfma_f32_16x16x32_f16(W3h[T][1], B2l[1].v, aL, 0, 0, 0);
                aL = __builtin_amdgcn_mfma_f32_16x16x32_f16(W3l[T][1], B2h[1].v, aL, 0, 0, 0);
                ZH[T] = aH; ZL[T] = aL;
            }
        }
        // ---- layer 4 (fp32), tangent-local: every lane computes
        // w4 . (1[primal z3 > 0] * own z3). On tangent lanes own z3 == dz3
        // and the mask bit is the fwd partner's primal sign -> TRUE g.
        // (fwd lanes produce garbage, overwritten by the final g-DPP.) ----
        {
            float zv[16];
            #pragma unroll
            for (int i = 0; i < 16; ++i)
                zv[i] = fmaf(ZL[i >> 2][i & 3], LOINV, ZH[i >> 2][i & 3]);
            float s0 = 0.f, s1 = 0.f, s2 = 0.f, s3 = 0.f;
            #pragma unroll
            for (int T = 0; T < 4; ++T) {
                const int i0 = T * 4;
                const unsigned long long m0 = __ballot(zv[i0 + 0] > 0.f);
                const unsigned long long m1 = __ballot(zv[i0 + 1] > 0.f);
                const unsigned long long m2 = __ballot(zv[i0 + 2] > 0.f);
                const unsigned long long m3 = __ballot(zv[i0 + 3] > 0.f);
                const unsigned long long t0 = m0 & FWDMASK;
                const unsigned long long t1 = m1 & FWDMASK;
                const unsigned long long t2 = m2 & FWDMASK;
                const unsigned long long t3 = m3 & FWDMASK;
                s0 = fmaf(w4r[i0 + 0], selmask(zv[i0 + 0], t0 | (t0 << 8)), s0);
                s1 = fmaf(w4r[i0 + 1], selmask(zv[i0 + 1], t1 | (t1 << 8)), s1);
                s2 = fmaf(w4r[i0 + 2], selmask(zv[i0 + 2], t2 | (t2 << 8)), s2);
                s3 = fmaf(w4r[i0 + 3], selmask(zv[i0 + 3], t3 | (t3 << 8)), s3);
            }
            float g = (s0 + s1) + (s2 + s3);
            g = bfly16(g);            // + lane^16 partner (VALU permlane)
            g = bfly32(g);            // + lane^32 partner (VALU permlane)
            const float gx = xor8f(g);
            g = fwd ? gx : g;         // fwd lanes take tangent's true g
            y -= 0.1f * g;
        }
    }
    if (lane < 8) out[sbase + lane] = y;
}

extern "C" void kernel_launch(void* const* d_in, const int* in_sizes, int n_in,
                              void* d_out, int out_size, void* d_ws, size_t ws_size,
                              hipStream_t stream) {
    const float* x  = (const float*)d_in[0];
    const float* c  = (const float*)d_in[1];
    const float* W1 = (const float*)d_in[2];
    const float* b1 = (const float*)d_in[3];
    const float* W2 = (const float*)d_in[4];
    const float* b2 = (const float*)d_in[5];
    const float* W3 = (const float*)d_in[6];
    const float* b3 = (const float*)d_in[7];
    const float* W4 = (const float*)d_in[8];
    // d_in[9] = b4: unused (only grad wrt y is needed, b4 drops out)
    float* out = (float*)d_out;

    solve_kernel<<<BATCH / 8, 64, 0, stream>>>(x, c, W1, b1, W2, b2, W3, b3, W4, out);
}

// Round 7
// 147.577 us; speedup vs baseline: 1.0222x; 1.0222x over previous
//
#include <hip/hip_runtime.h>

#define BATCH 8192
#define LOSC  2048.0f
#define LOINV (1.0f / 2048.0f)

typedef _Float16 f16x8 __attribute__((ext_vector_type(8)));
typedef __fp16   fp16x2 __attribute__((ext_vector_type(2)));
typedef float    f32x4 __attribute__((ext_vector_type(4)));

union PK2 { fp16x2 h; unsigned u; };
union U8  { f16x8 v; unsigned u[4]; };

// pack two f32 -> 2 f16 via v_cvt_pkrtz (RTZ is fine for hi/lo splitting:
// any hi with |v-hi| <= ulp works; lo carries the remainder, scaled 2^11)
__device__ __forceinline__ unsigned pkrtz(float a, float b) {
    PK2 p; p.h = __builtin_amdgcn_cvt_pkrtz(a, b); return p.u;
}

// Packed lo residual in 2 instrs/pair: f16x2{ (a-hi0)*2048, (b-hi1)*2048 }
// computed as fma(hi, -2048, v*2048) per half via v_fma_mixlo/hi_f16.
// Intermediate is f32-exact (v-hi Sterbenz-exact, *2048 exact).
__device__ __forceinline__ unsigned lopair(unsigned hipk, float am, float bm,
                                           float n2048) {
    unsigned d;
    asm("v_fma_mixlo_f16 %0, %1, %2, %3 op_sel:[0,0,0] op_sel_hi:[1,0,0]\n\t"
        "v_fma_mixhi_f16 %0, %1, %2, %4 op_sel:[1,0,0] op_sel_hi:[1,0,0]"
        : "=&v"(d)
        : "v"(hipk), "v"(n2048), "v"(am), "v"(bm));
    return d;
}

// lane i <-> lane i^8 exchange via DPP ROW_ROR:8 (rotate by 8 within each
// 16-lane row == xor-8, self-inverse). Single VALU mov, no DS pipe.
__device__ __forceinline__ float xor8f(float v) {
    const int r = __builtin_amdgcn_mov_dpp(__builtin_bit_cast(int, v),
                                           0x128 /*ROW_ROR:8*/, 0xf, 0xf, false);
    return __builtin_bit_cast(float, r);
}

// butterfly-sum with lane^16 / lane^32 partner via v_permlane16/32_swap.
// The opaque v_mov prevents the RA from coalescing a and b into one vreg
// (the R4 bug: a degenerate self-swap). After the swap the two regs jointly
// hold {own, partner} per lane, so a+b == g + g^N bitwise (fp add is
// commutative). Pure VALU — no DS pipe, no lgkmcnt.
__device__ __forceinline__ float bfly16(float g) {
    float a = g, b;
    asm volatile("v_mov_b32 %0, %1" : "=v"(b) : "v"(g));
    asm("v_permlane16_swap_b32 %0, %1" : "+v"(a), "+v"(b));
    return a + b;
}
__device__ __forceinline__ float bfly32(float g) {
    float a = g, b;
    asm volatile("v_mov_b32 %0, %1" : "=v"(b) : "v"(g));
    asm("v_permlane32_swap_b32 %0, %1" : "+v"(a), "+v"(b));
    return a + b;
}

// ---------------------------------------------------------------------------
// Fused kernel: NN prologue + 50-step GD solve. 8 samples/wave, 1024 blocks
// x 1 wave (1 wave/SIMD; grid-capped).
//
// R7 theory: persistent demand (128 VGPRs of weight fragments + ~90 other)
// exceeded the 256-VGPR wave ceiling -> compiler placed overflow in AGPRs
// (VGPR_Count=152 reported, rest hidden) -> per-step v_accvgpr moves +
// hazards explain VALUBusy ~2-3x the source instruction count and the ~65%
// stall fraction. Fix: ALL weight fragments live in LDS (reusing the dead
// 32KB cs[] NN buffer, [frag][lane] layout, conflict-free), re-read each
// step via 32 ds_read_b128 whose latency hides under L1/combine compute.
// An opaque asm on the index defeats LICM so loads stay in-loop.
// Gates reverted to R3's pure-VALU DPP form (R6's ballot->SALU->cndmask
// chains added cross-pipe latency for zero gain). bfly16/32 retained.
// K=32 MFMA layout as before (zero-shfl inter-layer transform).
// B cols = [8 fwd | 8 tangent].
// ---------------------------------------------------------------------------
__global__ __launch_bounds__(64, 1) void solve_kernel(
    const float* __restrict__ x, const float* __restrict__ c,
    const float* __restrict__ W1, const float* __restrict__ b1,
    const float* __restrict__ W2, const float* __restrict__ b2,
    const float* __restrict__ W3, const float* __restrict__ b3,
    const float* __restrict__ W4, float* __restrict__ out)
{
    const int lane  = threadIdx.x & 63;
    const int sbase = blockIdx.x * 8;
    const float n2048 = -2048.0f;

    // ---- stage all c into LDS (32 KiB; reused as weight store after NN) ----
    __shared__ float cs[BATCH];
    {
        const float4* cg = (const float4*)c;
        float4* cl = (float4*)cs;
        #pragma unroll
        for (int j = 0; j < BATCH / 4 / 64; ++j)
            cl[lane + j * 64] = cg[lane + j * 64];
    }
    __syncthreads();

    // ---- fused NN: 8 lanes per sample scan 2048 float4 each ----
    float c0s;
    {
        const int g  = lane >> 3;
        const int p  = lane & 7;
        const int si = sbase + g;
        const float ci = cs[si];
        const int sj0 = ((si & 3) == 0) ? (si >> 2) : -1;
        const int sj1 = ((si & 3) == 1) ? (si >> 2) : -1;
        const int sj2 = ((si & 3) == 2) ? (si >> 2) : -1;
        const int sj3 = ((si & 3) == 3) ? (si >> 2) : -1;
        const float4* cs4 = (const float4*)cs;
        float bd0 = 3e38f, bd1 = 3e38f, bd2 = 3e38f, bd3 = 3e38f;
        int   bj0 = 0,     bj1 = 0,     bj2 = 0,     bj3 = 0;
        #pragma unroll 1
        for (int big = 0; big < 16; ++big) {
            float4 vv[16];
            #pragma unroll
            for (int u = 0; u < 16; ++u)
                vv[u] = cs4[p + (big * 16 + u) * 8];
            #pragma unroll
            for (int u = 0; u < 16; ++u) {
                const int jj = p + (big * 16 + u) * 8;
                const float4 v = vv[u];
                float d0 = fabsf(ci - v.x);
                float d1 = fabsf(ci - v.y);
                float d2 = fabsf(ci - v.z);
                float d3 = fabsf(ci - v.w);
                if (jj == sj0) d0 = 3e38f;
                if (jj == sj1) d1 = 3e38f;
                if (jj == sj2) d2 = 3e38f;
                if (jj == sj3) d3 = 3e38f;
                if (d0 < bd0) { bd0 = d0; bj0 = jj; }
                if (d1 < bd1) { bd1 = d1; bj1 = jj; }
                if (d2 < bd2) { bd2 = d2; bj2 = jj; }
                if (d3 < bd3) { bd3 = d3; bj3 = jj; }
            }
        }
        float best = bd0; int bestj = bj0 * 4 + 0;
        { const int j1 = bj1 * 4 + 1; if (bd1 < best || (bd1 == best && j1 < bestj)) { best = bd1; bestj = j1; } }
        { const int j2 = bj2 * 4 + 2; if (bd2 < best || (bd2 == best && j2 < bestj)) { best = bd2; bestj = j2; } }
        { const int j3 = bj3 * 4 + 3; if (bd3 < best || (bd3 == best && j3 < bestj)) { best = bd3; bestj = j3; } }
        #pragma unroll
        for (int off = 1; off < 8; off <<= 1) {
            const float od = __shfl_xor(best, off);
            const int   oj = __shfl_xor(bestj, off);
            if (od < best || (od == best && oj < bestj)) { best = od; bestj = oj; }
        }
        const float bestc = cs[bestj];
        c0s = __shfl(bestc, (lane & 7) << 3);
    }

    // ---- GD solve ----
    const int q  = lane >> 4;
    const int cc = lane & 15;
    const bool fwd = (cc < 8);
    const int s = cc & 7;

    __syncthreads();   // NN reads of cs[] done; safe to overlay weights

    // ---- pack W2/W3 hi+lo fragments (K=32 chunks) INTO LDS ----
    // Layout: wfrag[(grp*8 + T*2 + M)*64 + lane], grp = {0:W2h,1:W2l,2:W3h,
    // 3:W3l}. 32 frags x 64 lanes x 16B = 32 KiB (== cs). Consecutive lanes
    // hold consecutive 16B -> conflict-free ds_write/read_b128.
    {
        f16x8* wfrag = (f16x8*)cs;
        #pragma unroll
        for (int T = 0; T < 4; ++T)
            #pragma unroll
            for (int M = 0; M < 2; ++M) {
                const int off0 = (T * 16 + cc) * 64 + M * 32 + q * 4;
                const int off1 = off0 + 16;
                const int f = T * 2 + M;
                float4 a = *(const float4*)(W2 + off0);
                float4 b = *(const float4*)(W2 + off1);
                U8 h, l;
                h.u[0] = pkrtz(a.x, a.y); h.u[1] = pkrtz(a.z, a.w);
                h.u[2] = pkrtz(b.x, b.y); h.u[3] = pkrtz(b.z, b.w);
                l.u[0] = lopair(h.u[0], a.x * LOSC, a.y * LOSC, n2048);
                l.u[1] = lopair(h.u[1], a.z * LOSC, a.w * LOSC, n2048);
                l.u[2] = lopair(h.u[2], b.x * LOSC, b.y * LOSC, n2048);
                l.u[3] = lopair(h.u[3], b.z * LOSC, b.w * LOSC, n2048);
                wfrag[(0 * 8 + f) * 64 + lane] = h.v;
                wfrag[(1 * 8 + f) * 64 + lane] = l.v;
                a = *(const float4*)(W3 + off0);
                b = *(const float4*)(W3 + off1);
                h.u[0] = pkrtz(a.x, a.y); h.u[1] = pkrtz(a.z, a.w);
                h.u[2] = pkrtz(b.x, b.y); h.u[3] = pkrtz(b.z, b.w);
                l.u[0] = lopair(h.u[0], a.x * LOSC, a.y * LOSC, n2048);
                l.u[1] = lopair(h.u[1], a.z * LOSC, a.w * LOSC, n2048);
                l.u[2] = lopair(h.u[2], b.x * LOSC, b.y * LOSC, n2048);
                l.u[3] = lopair(h.u[3], b.z * LOSC, b.w * LOSC, n2048);
                wfrag[(2 * 8 + f) * 64 + lane] = h.v;
                wfrag[(3 * 8 + f) * 64 + lane] = l.v;
            }
    }
    __syncthreads();   // LDS writes complete before loop reads

    // ---- biases as f32x4 (direct MFMA C-operands) + W4 rows ----
    f32x4 b2q[4], b3q[4];
    const f32x4 zq = {0.f, 0.f, 0.f, 0.f};
    float w4r[16];
    #pragma unroll
    for (int T = 0; T < 4; ++T)
        #pragma unroll
        for (int r = 0; r < 4; ++r) {
            const int row = T * 16 + q * 4 + r;
            b2q[T][r] = fwd ? b2[row] : 0.f;
            b3q[T][r] = fwd ? b3[row] : 0.f;
            w4r[T * 4 + r] = W4[row];
        }

    // ---- layer-1 constants: logical k = m*16 + q*4 + j ----
    float A1v[16], w11v[16];
    {
        const float xs = x[sbase + s];
        #pragma unroll
        for (int m = 0; m < 4; ++m)
            #pragma unroll
            for (int j = 0; j < 4; ++j) {
                const int k = m * 16 + q * 4 + j;
                w11v[m * 4 + j] = W1[k * 3 + 1];
                A1v[m * 4 + j]  = fmaf(xs, W1[k * 3 + 0],
                                       fmaf(c0s, W1[k * 3 + 2], b1[k]));
            }
    }

    const f16x8* __restrict__ wfrag = (const f16x8*)cs;
    int wbase = lane;   // per-lane fragment base; made opaque each iteration

    float y = 0.0f;

    #pragma unroll 1
    for (int step = 0; step < 50; ++step) {
        asm("" : "+v"(wbase));   // defeat LICM: weight loads stay in-loop

        // ---- W2 fragments from LDS (latency hides under L1 compute) ----
        f16x8 w2h_[4][2], w2l_[4][2];
        #pragma unroll
        for (int T = 0; T < 4; ++T)
            #pragma unroll
            for (int M = 0; M < 2; ++M) {
                const int f = T * 2 + M;
                w2h_[T][M] = wfrag[(0 * 8 + f) * 64 + wbase];
                w2l_[T][M] = wfrag[(1 * 8 + f) * 64 + wbase];
            }

        // ---- layer 1 (fp32, registers) -> split B1 chunks (2 x K=32) ----
        U8 B1h[2], B1l[2];
        #pragma unroll
        for (int m = 0; m < 4; ++m) {
            float v[4];
            #pragma unroll
            for (int j = 0; j < 4; ++j) {
                const float w = w11v[m * 4 + j];
                const float z = fmaf(y, w, A1v[m * 4 + j]);
                const float a = fwd ? z : w;
                v[j] = (z > 0.f) ? a : 0.f;
            }
            const unsigned h0 = pkrtz(v[0], v[1]);
            const unsigned h1 = pkrtz(v[2], v[3]);
            const int M = m >> 1, o = (m & 1) * 2;
            B1h[M].u[o]     = h0;
            B1h[M].u[o + 1] = h1;
            B1l[M].u[o]     = lopair(h0, v[0] * LOSC, v[1] * LOSC, n2048);
            B1l[M].u[o + 1] = lopair(h1, v[2] * LOSC, v[3] * LOSC, n2048);
        }
        // ---- layer 2: split MFMA (bias rides in as C-operand) ----
        f32x4 ZH[4], ZL[4];
        #pragma unroll
        for (int T = 0; T < 4; ++T) {
            f32x4 aH = __builtin_amdgcn_mfma_f32_16x16x32_f16(w2h_[T][0], B1h[0].v, b2q[T], 0, 0, 0);
            f32x4 aL = __builtin_amdgcn_mfma_f32_16x16x32_f16(w2h_[T][0], B1l[0].v, zq, 0, 0, 0);
            aL = __builtin_amdgcn_mfma_f32_16x16x32_f16(w2l_[T][0], B1h[0].v, aL, 0, 0, 0);
            aH = __builtin_amdgcn_mfma_f32_16x16x32_f16(w2h_[T][1], B1h[1].v, aH, 0, 0, 0);
            aL = __builtin_amdgcn_mfma_f32_16x16x32_f16(w2h_[T][1], B1l[1].v, aL, 0, 0, 0);
            aL = __builtin_amdgcn_mfma_f32_16x16x32_f16(w2l_[T][1], B1h[1].v, aL, 0, 0, 0);
            ZH[T] = aH; ZL[T] = aL;
        }

        // ---- W3 fragments from LDS (latency hides under combine1) ----
        f16x8 w3h_[4][2], w3l_[4][2];
        #pragma unroll
        for (int T = 0; T < 4; ++T)
            #pragma unroll
            for (int M = 0; M < 2; ++M) {
                const int f = T * 2 + M;
                w3h_[T][M] = wfrag[(2 * 8 + f) * 64 + wbase];
                w3l_[T][M] = wfrag[(3 * 8 + f) * 64 + wbase];
            }

        // ---- combine1 (DPP exchange) + mask -> B2 chunks ----
        {
            float zv[16], rv[16];
            #pragma unroll
            for (int i = 0; i < 16; ++i)
                zv[i] = fmaf(ZL[i >> 2][i & 3], LOINV, ZH[i >> 2][i & 3]);
            #pragma unroll
            for (int i = 0; i < 16; ++i)
                rv[i] = xor8f(zv[i]);            // VALU DPP, no DS pipe
            U8 B2h[2], B2l[2];
            #pragma unroll
            for (int T = 0; T < 4; ++T) {
                float v[4];
                #pragma unroll
                for (int r = 0; r < 4; ++r) {
                    const float z = zv[T * 4 + r];
                    const float gate = fwd ? z : rv[T * 4 + r];
                    v[r] = (gate > 0.f) ? z : 0.f;
                }
                const unsigned h0 = pkrtz(v[0], v[1]);
                const unsigned h1 = pkrtz(v[2], v[3]);
                const int M = T >> 1, o = (T & 1) * 2;
                B2h[M].u[o]     = h0;
                B2h[M].u[o + 1] = h1;
                B2l[M].u[o]     = lopair(h0, v[0] * LOSC, v[1] * LOSC, n2048);
                B2l[M].u[o + 1] = lopair(h1, v[2] * LOSC, v[3] * LOSC, n2048);
            }
            // ---- layer 3: split MFMA ----
            #pragma unroll
            for (int T = 0; T < 4; ++T) {
                f32x4 aH = __builtin_amdgcn_mfma_f32_16x16x32_f16(w3h_[T][0], B2h[0].v, b3q[T], 0, 0, 0);
                f32x4 aL = __builtin_amdgcn_mfma_f32_16x16x32_f16(w3h_[T][0], B2l[0].v, zq, 0, 0, 0);
                aL = __builtin_amdgcn_mfma_f32_16x16x32_f16(w3l_[T][0], B2h[0].v, aL, 0, 0, 0);
                aH = __builtin_amdgcn_mfma_f32_16x16x32_f16(w3h_[T][1], B2h[1].v, aH, 0, 0, 0);
                aL = __builtin_amdgcn_mfma_f32_16x16x32_f16(w3h_[T][1], B2l[1].v, aL, 0, 0, 0);
                aL = __builtin_amdgcn_mfma_f32_16x16x32_f16(w3l_[T][1], B2h[1].v, aL, 0, 0, 0);
                ZH[T] = aH; ZL[T] = aL;
            }
        }
        // ---- layer 4 (fp32): g = W4 . (1[z3>0] * dz3), 4 parallel chains ----
        {
            float zv[16], rv[16];
            #pragma unroll
            for (int i = 0; i < 16; ++i)
                zv[i] = fmaf(ZL[i >> 2][i & 3], LOINV, ZH[i >> 2][i & 3]);
            #pragma unroll
            for (int i = 0; i < 16; ++i)
                rv[i] = xor8f(zv[i]);            // VALU DPP, no DS pipe
            float s0 = 0.f, s1 = 0.f, s2 = 0.f, s3 = 0.f;
            #pragma unroll
            for (int T = 0; T < 4; ++T) {
                const int i0 = T * 4;
                const float g0 = fwd ? zv[i0 + 0] : rv[i0 + 0];
                const float g1 = fwd ? zv[i0 + 1] : rv[i0 + 1];
                const float g2 = fwd ? zv[i0 + 2] : rv[i0 + 2];
                const float g3 = fwd ? zv[i0 + 3] : rv[i0 + 3];
                const float v0 = fwd ? rv[i0 + 0] : zv[i0 + 0];
                const float v1 = fwd ? rv[i0 + 1] : zv[i0 + 1];
                const float v2 = fwd ? rv[i0 + 2] : zv[i0 + 2];
                const float v3 = fwd ? rv[i0 + 3] : zv[i0 + 3];
                s0 = fmaf(w4r[i0 + 0], (g0 > 0.f) ? v0 : 0.f, s0);
                s1 = fmaf(w4r[i0 + 1], (g1 > 0.f) ? v1 : 0.f, s1);
                s2 = fmaf(w4r[i0 + 2], (g2 > 0.f) ? v2 : 0.f, s2);
                s3 = fmaf(w4r[i0 + 3], (g3 > 0.f) ? v3 : 0.f, s3);
            }
            float g = (s0 + s1) + (s2 + s3);
            g = bfly16(g);            // + lane^16 partner (VALU permlane)
            g = bfly32(g);            // + lane^32 partner (VALU permlane)
            y -= 0.1f * g;
        }
    }
    if (lane < 8) out[sbase + lane] = y;
}

extern "C" void kernel_launch(void* const* d_in, const int* in_sizes, int n_in,
                              void* d_out, int out_size, void* d_ws, size_t ws_size,
                              hipStream_t stream) {
    const float* x  = (const float*)d_in[0];
    const float* c  = (const float*)d_in[1];
    const float* W1 = (const float*)d_in[2];
    const float* b1 = (const float*)d_in[3];
    const float* W2 = (const float*)d_in[4];
    const float* b2 = (const float*)d_in[5];
    const float* W3 = (const float*)d_in[6];
    const float* b3 = (const float*)d_in[7];
    const float* W4 = (const float*)d_in[8];
    // d_in[9] = b4: unused (only grad wrt y is needed, b4 drops out)
    float* out = (float*)d_out;

    solve_kernel<<<BATCH / 8, 64, 0, stream>>>(x, c, W1, b1, W2, b2, W3, b3, W4, out);
}